// Round 6
// baseline (64136.633 us; speedup 1.0000x reference)
//
#include <hip/hip_runtime.h>
#include <hip/hip_bf16.h>

#define NB 4096
#define MDIM 327
#define NDIM 800
#define NLAYERS 9
#define NPIX 800
#define CHN 32
#define NBP (NB * NPIX)

typedef __hip_bfloat16 bf16;

// ---------------- setup ----------------

__global__ void k_copy(const float* __restrict__ src, float* __restrict__ dst,
                       long long n) {
    long long i0 = (long long)blockIdx.x * 256 + threadIdx.x;
    long long stride = (long long)gridDim.x * 256;
    for (long long i = i0; i < n; i += stride) dst[i] = src[i];
}

// transpose [O=32][I*9=288] -> [288][32]
__global__ void k_wtrans(const float* __restrict__ src, float* __restrict__ dst) {
    int idx = blockIdx.x * 256 + threadIdx.x;
    if (idx >= 9216) return;
    int o = idx / 288, r = idx % 288;
    dst[r * 32 + o] = src[idx];
}

__global__ void k_phitphi(const float* __restrict__ W, float* __restrict__ P) {
    int b = blockIdx.x * 16 + threadIdx.x;
    int a = blockIdx.y * 16 + threadIdx.y;
    float acc = 0.f;
    for (int k = 0; k < MDIM; ++k)
        acc += W[k * NDIM + a] * W[k * NDIM + b];
    P[(size_t)a * NDIM + b] = acc;
}

__global__ void k_wloss(const float* __restrict__ W, float* __restrict__ out) {
    int idx = blockIdx.x * 256 + threadIdx.x;
    if (idx >= MDIM * MDIM) return;
    int a = idx / MDIM, b = idx % MDIM;
    float acc = 0.f;
    for (int n = 0; n < NDIM; ++n)
        acc += W[a * NDIM + n] * W[b * NDIM + n];
    if (a == b) acc -= 1.f;
    out[idx] = acc;
}

__global__ void k_phitb(const float* __restrict__ y, const float* __restrict__ W,
                        float* __restrict__ PB) {
    int idx = blockIdx.x * 256 + threadIdx.x;
    if (idx >= NBP) return;
    int b = idx / NDIM, n = idx % NDIM;
    float acc = 0.f;
    for (int k = 0; k < MDIM; ++k)
        acc += y[b * MDIM + k] * W[k * NDIM + n];
    PB[idx] = acc;
}

// ---------------- X update ----------------

__global__ void k_x0(const float* __restrict__ PB, float* __restrict__ X1,
                     const float* __restrict__ hv) {
    int idx = blockIdx.x * 256 + threadIdx.x;
    if (idx >= NBP) return;
    X1[idx] = hv[0] * PB[idx];
}

// H = hatx = (1+tx)*Xc - tx*Xp
__global__ void k_hatx(const float* __restrict__ Xc, const float* __restrict__ Xp,
                       float* __restrict__ H, const float* __restrict__ txv,
                       int layer, int mode) {
    int idx = blockIdx.x * 256 + threadIdx.x;
    if (idx >= NBP) return;
    float tx = txv[layer];
    float xc = Xc[idx];
    float xp = (mode >= 2) ? Xp[idx] : 0.f;
    H[idx] = (1.f + tx) * xc - tx * xp;
}

// Xn = H*(1-h*b1) + h*PB - h*(H@P) + h*b1*Z - h*L
__global__ void k_xmm(const float* __restrict__ H, const float* __restrict__ P,
                      const float* __restrict__ PB, const float* __restrict__ Lc,
                      const float* __restrict__ Zc, float* __restrict__ Xn,
                      const float* __restrict__ hv, const float* __restrict__ b1v,
                      int layer, int mode) {
    __shared__ float As[64][17];
    __shared__ float Bs[16][65];
    int tid = threadIdx.x;
    float h = hv[layer], b1 = b1v[layer];
    int rowbase = blockIdx.y * 64, colbase = blockIdx.x * 64;
    int ttx = tid % 16, tty = tid / 16;
    float acc[4][4];
#pragma unroll
    for (int r = 0; r < 4; ++r)
#pragma unroll
        for (int c = 0; c < 4; ++c) acc[r][c] = 0.f;

    int am = tid >> 2, ak4 = (tid & 3) * 4;
    int bk = tid >> 4, bn4 = (tid & 15) * 4;

    for (int kt = 0; kt < 50; ++kt) {
        int k0 = kt * 16;
        {
            const float* hp = H + (size_t)(rowbase + am) * NDIM + k0 + ak4;
#pragma unroll
            for (int j = 0; j < 4; ++j) As[am][ak4 + j] = hp[j];
        }
        {
            const float* pr = P + (size_t)(k0 + bk) * NDIM + colbase + bn4;
#pragma unroll
            for (int j = 0; j < 4; ++j) {
                int col = colbase + bn4 + j;
                Bs[bk][bn4 + j] = (col < NDIM) ? pr[j] : 0.f;
            }
        }
        __syncthreads();
#pragma unroll
        for (int kk = 0; kk < 16; ++kk) {
            float a[4], b[4];
#pragma unroll
            for (int r = 0; r < 4; ++r) a[r] = As[tty * 4 + r][kk];
#pragma unroll
            for (int c = 0; c < 4; ++c) b[c] = Bs[kk][ttx * 4 + c];
#pragma unroll
            for (int r = 0; r < 4; ++r)
#pragma unroll
                for (int c = 0; c < 4; ++c) acc[r][c] += a[r] * b[c];
        }
        __syncthreads();
    }

#pragma unroll
    for (int r = 0; r < 4; ++r) {
        int row = rowbase + tty * 4 + r;
#pragma unroll
        for (int c = 0; c < 4; ++c) {
            int col = colbase + ttx * 4 + c;
            if (col >= NDIM) continue;
            size_t idx = (size_t)row * NDIM + col;
            float hx = H[idx];
            float zt = (mode == 2) ? Zc[idx] : 0.f;
            float lt = (mode == 2) ? Lc[idx] : 0.f;
            Xn[idx] = hx * (1.f - h * b1) + h * PB[idx] - h * acc[r][c] + h * b1 * zt - h * lt;
        }
    }
}

// ---------------- z_flat ----------------

__global__ void k_zflat(const float* __restrict__ Xn, const float* __restrict__ Zc,
                        const float* __restrict__ Zp, const float* __restrict__ Lc,
                        float* __restrict__ zf,
                        const float* __restrict__ hv, const float* __restrict__ b2v,
                        const float* __restrict__ tzv, int layer, int mode) {
    int idx = blockIdx.x * 256 + threadIdx.x;
    if (idx >= NBP) return;
    float h = hv[layer], b2 = b2v[layer], tz = tzv[layer];
    float hatz, lt;
    if (mode == 0) { hatz = 0.f; lt = 0.f; }
    else if (mode == 1) { hatz = (1.f + tz) * Zc[idx]; lt = 0.f; }
    else {
        float zc = Zc[idx], zp = Zp[idx];
        hatz = zc + tz * (zc - zp);
        lt = Lc[idx];
    }
    zf[idx] = hatz + h * (lt + b2 * (Xn[idx] - hatz));
}

// ---------------- convs (f32) ----------------

__global__ void k_conv1f(const float* __restrict__ zf, float* __restrict__ out,
                         const float* __restrict__ w, int c0) {
    __shared__ float zs[22 * 42];
    __shared__ float ws[288];
    int img = c0 + blockIdx.x;
    int tid = threadIdx.x;
    for (int i = tid; i < 288; i += 256) ws[i] = w[i];
    for (int i = tid; i < 22 * 42; i += 256) zs[i] = 0.f;
    __syncthreads();
    for (int p = tid; p < NPIX; p += 256) {
        int y = p / 40, x = p % 40;
        zs[(y + 1) * 42 + (x + 1)] = zf[(size_t)img * NPIX + p];
    }
    __syncthreads();
    for (int q = tid; q < CHN * NPIX; q += 256) {
        int o = q / NPIX, p = q % NPIX;
        int y = p / 40, x = p % 40;
        const float* wo = ws + o * 9;
        float s = 0.f;
#pragma unroll
        for (int ky = 0; ky < 3; ++ky)
#pragma unroll
            for (int kx = 0; kx < 3; ++kx)
                s += wo[ky * 3 + kx] * zs[(y + ky) * 42 + (x + kx)];
        out[(size_t)blockIdx.x * 25600 + q] = fmaxf(s, 0.f);
    }
}

// 32->32 conv, row-split 2 LDS passes. wT: [i*9+ky*3+kx][o].
__global__ void k_conv32(const float* __restrict__ in, float* __restrict__ out,
                         const float* __restrict__ wT, const float* __restrict__ thrv,
                         int layer, int softflag, int reluflag) {
    __shared__ float inS[CHN * 12 * 40];
    int tid = threadIdx.x;
    const float* ip = in + (size_t)blockIdx.x * 25600;
    float thr = softflag ? fabsf(thrv[layer]) : 0.f;
    int o = tid & 15;
    int pg = tid >> 4;
    for (int half = 0; half < 2; ++half) {
        int r0 = half * 10 - 1;
        for (int idx = tid; idx < CHN * 480; idx += 256) {
            int c = idx / 480, rr = (idx / 40) % 12, x = idx % 40;
            int gr = r0 + rr;
            float v = 0.f;
            if (gr >= 0 && gr < 20) {
                v = ip[c * 800 + gr * 40 + x];
                if (softflag) {
                    float a = fabsf(v) - thr;
                    v = (a > 0.f) ? copysignf(a, v) : 0.f;
                }
            }
            inS[idx] = v;
        }
        __syncthreads();
        for (int g = pg; g < 50; g += 16) {
            int ry = g / 5;
            int gx = (g % 5) * 8;
            float a0[8], a1[8];
#pragma unroll
            for (int j = 0; j < 8; ++j) { a0[j] = 0.f; a1[j] = 0.f; }
            for (int ci = 0; ci < CHN; ++ci) {
                const float* base = inS + ci * 480 + ry * 40;
#pragma unroll
                for (int ky = 0; ky < 3; ++ky) {
                    const float* row = base + ky * 40;
                    float pv[10];
#pragma unroll
                    for (int j = 0; j < 10; ++j) {
                        int rx = gx - 1 + j;
                        pv[j] = (rx >= 0 && rx < 40) ? row[rx] : 0.f;
                    }
                    const float* w0 = wT + (size_t)(ci * 9 + ky * 3) * 32 + o;
                    float wa0 = w0[0],  wb0 = w0[32], wc0 = w0[64];
                    float wa1 = w0[16], wb1 = w0[48], wc1 = w0[80];
#pragma unroll
                    for (int j = 0; j < 8; ++j) {
                        a0[j] += wa0 * pv[j] + wb0 * pv[j + 1] + wc0 * pv[j + 2];
                        a1[j] += wa1 * pv[j] + wb1 * pv[j + 1] + wc1 * pv[j + 2];
                    }
                }
            }
            int orow = half * 10 + ry;
            float* op0 = out + (size_t)blockIdx.x * 25600 + o * 800 + orow * 40 + gx;
            float* op1 = op0 + 16 * 800;
#pragma unroll
            for (int j = 0; j < 8; ++j) {
                float v0 = a0[j], v1 = a1[j];
                if (reluflag) { v0 = fmaxf(v0, 0.f); v1 = fmaxf(v1, 0.f); }
                op0[j] = v0;
                op1[j] = v1;
            }
        }
        __syncthreads();
    }
}

// 32->1 conv; writes f32 to global output (Zs or syms region); optional -z_in.
__global__ void k_conv2b(const float* __restrict__ in, const float* __restrict__ w,
                         const float* __restrict__ zf, float* __restrict__ out,
                         int subz, int c0) {
    __shared__ float inS[CHN * 12 * 40];
    __shared__ float ws[288];
    int tid = threadIdx.x;
    int img = c0 + blockIdx.x;
    const float* ip = in + (size_t)blockIdx.x * 25600;
    for (int i = tid; i < 288; i += 256) ws[i] = w[i];
    for (int half = 0; half < 2; ++half) {
        int r0 = half * 10 - 1;
        for (int idx = tid; idx < CHN * 480; idx += 256) {
            int c = idx / 480, rr = (idx / 40) % 12, x = idx % 40;
            int gr = r0 + rr;
            inS[idx] = (gr >= 0 && gr < 20) ? ip[c * 800 + gr * 40 + x] : 0.f;
        }
        __syncthreads();
        for (int q = tid; q < 400; q += 256) {
            int ry = q / 40, x = q % 40;
            float s = 0.f;
            for (int ci = 0; ci < CHN; ++ci) {
                const float* base = inS + ci * 480 + ry * 40;
                const float* wi = ws + ci * 9;
#pragma unroll
                for (int ky = 0; ky < 3; ++ky) {
                    const float* row = base + ky * 40;
#pragma unroll
                    for (int kx = 0; kx < 3; ++kx) {
                        int rx = x - 1 + kx;
                        if (rx >= 0 && rx < 40) s += wi[ky * 3 + kx] * row[rx];
                    }
                }
            }
            int p = (half * 10 + ry) * 40 + x;
            size_t gidx = (size_t)img * NPIX + p;
            if (subz) s -= zf[gidx];
            out[gidx] = s;
        }
        __syncthreads();
    }
}

// ---------------- L update ----------------

__global__ void k_lup(const float* __restrict__ Xn, const float* __restrict__ Zn,
                      const float* __restrict__ Lc, const float* __restrict__ Lp,
                      float* __restrict__ Ln,
                      const float* __restrict__ hv, const float* __restrict__ b1v,
                      const float* __restrict__ tLv, int layer, int mode) {
    int idx = blockIdx.x * 256 + threadIdx.x;
    if (idx >= NBP) return;
    float h = hv[layer], b1 = b1v[layer], tL = tLv[layer];
    float hatL;
    if (mode == 0) hatL = 0.f;
    else if (mode == 1) hatL = (1.f + tL) * Lc[idx];
    else {
        float lc = Lc[idx], lp = Lp[idx];
        hatL = lc + tL * (lc - lp);
    }
    Ln[idx] = hatL + h * b1 * (Xn[idx] - Zn[idx]);
}

// ---------------- host ----------------
// PROBE-VERIFIED (round 5): inputs f32, dict order, n_in=14, output f32, ws>=120MB.

extern "C" void kernel_launch(void* const* d_in, const int* in_sizes, int n_in,
                              void* d_out, int out_size, void* d_ws, size_t ws_size,
                              hipStream_t stream) {
    const float* y    = (const float*)d_in[0];
    const float* Wf   = (const float*)d_in[2];
    const float* b1v  = (const float*)d_in[3];
    const float* b2v  = (const float*)d_in[4];
    const float* hv   = (const float*)d_in[5];
    const float* stv  = (const float*)d_in[6];
    const float* txv  = (const float*)d_in[7];
    const float* tzv  = (const float*)d_in[8];
    const float* tLv  = (const float*)d_in[9];
    const float* w1f  = (const float*)d_in[10];
    const float* w2f  = (const float*)d_in[11];
    const float* w1b  = (const float*)d_in[12];
    const float* w2b  = (const float*)d_in[13];

    float* Zout  = (float*)d_out;                       // [9][NBP]
    float* Sout  = Zout + (size_t)NLAYERS * NBP;        // [9][NBP]
    float* WLout = Zout + 2 * (size_t)NLAYERS * NBP;    // [327*327]

    char* ws = (char*)d_ws;
    size_t off = 0;
    auto alloc = [&](size_t bytes) -> void* {
        void* p = ws + off;
        off += (bytes + 255) & ~(size_t)255;
        return p;
    };

    float* w2fT = (float*)alloc(9216 * 4);
    float* w1bT = (float*)alloc(9216 * 4);
    float* P    = (float*)alloc((size_t)NDIM * NDIM * 4);
    float* PB   = (float*)alloc((size_t)NBP * 4);
    float* Xa   = (float*)alloc((size_t)NBP * 4);
    float* Xb_  = (float*)alloc((size_t)NBP * 4);
    float* La   = (float*)alloc((size_t)NBP * 4);
    float* Lb_  = (float*)alloc((size_t)NBP * 4);
    float* zfb  = (float*)alloc((size_t)NBP * 4);   // doubles as hatx temp

    size_t rem = (ws_size > off + 4096) ? (ws_size - off - 4096) : 0;
    long long Ci = (long long)(rem / (2 * 25600 * 4));
    if (Ci > 2048) Ci = 2048;
    if (Ci < 1) Ci = 1;
    int C = (int)Ci;
    float* Abuf = (float*)alloc((size_t)C * 25600 * 4);
    float* Bbuf = (float*)alloc((size_t)C * 25600 * 4);

    int ew_grid = (NBP + 255) / 256;

    k_wtrans<<<36, 256, 0, stream>>>(w2f, w2fT);
    k_wtrans<<<36, 256, 0, stream>>>(w1b, w1bT);
    k_phitphi<<<dim3(50, 50), dim3(16, 16), 0, stream>>>(Wf, P);
    k_wloss<<<(MDIM * MDIM + 255) / 256, 256, 0, stream>>>(Wf, WLout);
    k_phitb<<<ew_grid, 256, 0, stream>>>(y, Wf, PB);

    float* Xcur = Xa; float* Xoth = Xb_;
    float* Lcur = La; float* Loth = Lb_;

    for (int i = 0; i < NLAYERS; ++i) {
        int mode = (i == 0) ? 0 : ((i == 1) ? 1 : 2);
        float* Zw = Zout + (size_t)i * NBP;
        const float* Zc = Zout + (size_t)((i >= 1) ? (i - 1) : 0) * NBP;
        const float* Zp = Zout + (size_t)((i >= 2) ? (i - 2) : 0) * NBP;

        float* Xn;
        if (i == 0) {
            Xn = Xcur;
            k_x0<<<ew_grid, 256, 0, stream>>>(PB, Xn, hv);
        } else {
            k_hatx<<<ew_grid, 256, 0, stream>>>(Xcur, Xoth, zfb, txv, i, mode);
            Xn = Xoth;
            k_xmm<<<dim3(13, 64), 256, 0, stream>>>(zfb, P, PB, Lcur, Zc, Xn,
                                                    hv, b1v, i, mode);
            float* t = Xcur; Xcur = Xn; Xoth = t;
        }

        k_zflat<<<ew_grid, 256, 0, stream>>>(Xn, Zc, Zp, Lcur, zfb, hv, b2v, tzv, i, mode);

        for (int c0 = 0; c0 < NB; c0 += C) {
            int g = (NB - c0 < C) ? (NB - c0) : C;
            k_conv1f<<<g, 256, 0, stream>>>(zfb, Abuf, w1f, c0);
            k_conv32<<<g, 256, 0, stream>>>(Abuf, Bbuf, w2fT, stv, i, 0, 0);   // x_fwd
            k_conv32<<<g, 256, 0, stream>>>(Bbuf, Abuf, w1bT, stv, i, 1, 1);   // relu(c1b(soft(x_fwd)))
            k_conv2b<<<g, 256, 0, stream>>>(Abuf, w2b, zfb, Zw, 0, c0);        // Zs[i]
            k_conv32<<<g, 256, 0, stream>>>(Bbuf, Abuf, w1bT, stv, i, 0, 1);   // relu(c1b(x_fwd))
            k_conv2b<<<g, 256, 0, stream>>>(Abuf, w2b, zfb, Sout + (size_t)i * NBP, 1, c0); // syms[i]
        }

        k_lup<<<ew_grid, 256, 0, stream>>>(Xn, Zw, Lcur, Loth, Loth, hv, b1v, tLv, i, mode);
        { float* t = Lcur; Lcur = Loth; Loth = t; }
    }
}